// Round 7
// baseline (317.878 us; speedup 1.0000x reference)
//
#include <hip/hip_runtime.h>
#include <hip/hip_bf16.h>

#define B_ 4
#define N_ 4096
#define D_ 1024
#define H_ 16

typedef __attribute__((ext_vector_type(4))) float f32x4;
typedef __attribute__((ext_vector_type(8))) short s16x8;
typedef __attribute__((ext_vector_type(4))) unsigned int u32x4;

__device__ __forceinline__ ushort f2bf(float f) {
  union { float f; unsigned u; } v; v.f = f;
  unsigned u = v.u;
  return (ushort)((u + 0x7fffu + ((u >> 16) & 1u)) >> 16);
}

__device__ __forceinline__ void gld16(const ushort* g, ushort* lds_base) {
  __builtin_amdgcn_global_load_lds(
      (const __attribute__((address_space(1))) unsigned int*)g,
      (__attribute__((address_space(3))) unsigned int*)lds_base, 16, 0, 0);
}

__device__ __forceinline__ unsigned cvtpk(float lo, float hi) {
  unsigned r;
  asm("v_cvt_pk_bf16_f32 %0, %1, %2" : "=v"(r) : "v"(lo), "v"(hi));
  return r;
}

#define WAITVM(N) asm volatile("s_waitcnt vmcnt(" #N ")" ::: "memory")
#define LGKM0 asm volatile("s_waitcnt lgkmcnt(0)" ::: "memory")
#define SBAR __builtin_amdgcn_sched_barrier(0)
#define BARRIER __builtin_amdgcn_s_barrier()

// ---------------- weight convert ----------------
__global__ void conv_w_kernel(const float* __restrict__ w0, const float* __restrict__ w1,
                              const float* __restrict__ w2, const float* __restrict__ w3,
                              ushort* __restrict__ dst) {
  const int z = blockIdx.z;
  const float* src = z == 0 ? w0 : z == 1 ? w1 : z == 2 ? w2 : w3;
  ushort* d = dst + (long)z * (D_ * D_);
  const long i0 = ((long)blockIdx.x * 256 + threadIdx.x) * 8;
  const long STR = (long)128 * 256 * 8;
#pragma unroll
  for (int u = 0; u < 4; ++u) {
    f32x4 a = *(const f32x4*)(src + i0 + u * STR);
    f32x4 b = *(const f32x4*)(src + i0 + u * STR + 4);
    s16x8 o;
    o[0] = (short)f2bf(a[0]); o[1] = (short)f2bf(a[1]); o[2] = (short)f2bf(a[2]); o[3] = (short)f2bf(a[3]);
    o[4] = (short)f2bf(b[0]); o[5] = (short)f2bf(b[1]); o[6] = (short)f2bf(b[2]); o[7] = (short)f2bf(b[3]);
    *(s16x8*)(d + i0 + u * STR) = o;
  }
}

// ---------------- gemm: C[m,n] = sum_k A[m,k]*B[n,k], K=1024 ----------------
// 256x256 tile, BK=32, 512 threads = 8 waves (2M x 4N), per-wave out 128x64.
// LDS: A,B 4 bufs x [256][32] bf16 (swizzled slot = rawslot ^ ((row>>1)&3)).
// Depth-3 prefetch, counted vmcnt, 1 barrier/step, setprio around MFMA.
// EPI: 0 = bf16 store (V), 1 = +bias head-softmax *1/8 (Q), 2 = exp + col partials (K),
//      3 = +bias fp32 store (final)
template <int EPI, bool AFP32>
__global__ __launch_bounds__(512, 2) void gemm_bt_kernel(
    const void* __restrict__ Av, const ushort* __restrict__ Bm,
    void* __restrict__ Cv, const float* __restrict__ bias, float* __restrict__ kpart,
    long sA, long sB, long sC) {
  __shared__ ushort As[32768];  // 4 bufs x 8192 ushorts
  __shared__ ushort Bs[32768];
  const int z = blockIdx.z;
  Bm += (long)z * sB;
  const int m0 = blockIdx.x * 256, n0 = blockIdx.y * 256;
  const int N = 1024;
  const int tid = threadIdx.x;
  const int lane = tid & 63;
  const int wave = tid >> 6;
  const int fl = lane & 15, fh = lane >> 4;
  const int wm = wave >> 2, wn = wave & 3;   // 2M x 4N
  f32x4 acc[8][4] = {};

  // swizzled fragment-read slot (same for all frags: (row>>1)&3 == (fl>>1)&3)
  const int fro = (fh ^ ((fl >> 1) & 3)) * 8;
  const int rmb = (wm * 128 + fl) * 32;
  const int rnb = (wn * 64 + fl) * 32;

  // B staging: 2 chunks/thread/step; dest linear c*16B, source col inverse-swizzled
  const int brow = tid >> 2;
  const int bslot = ((tid & 3) ^ ((brow >> 1) & 3)) * 8;
  const ushort* Bsrc0 = Bm + (long)(n0 + brow) * 1024 + bslot;
  const ushort* Bsrc1 = Bm + (long)(n0 + brow + 128) * 1024 + bslot;

  // A bf16 staging (EPI==3 path)
  const ushort* Ab = AFP32 ? nullptr : ((const ushort*)Av + (long)z * sA);
  const ushort* Asrc0 = AFP32 ? nullptr : (Ab + (long)(m0 + brow) * 1024 + bslot);
  const ushort* Asrc1 = AFP32 ? nullptr : (Ab + (long)(m0 + brow + 128) * 1024 + bslot);

  // A fp32 reg staging: row ar, col-half ch (16 floats), swizzled ds_write_b128 x2
  const int ar = tid >> 1, ch = tid & 1;
  const float* apA = AFP32 ? ((const float*)Av + (long)(m0 + ar) * 1024 + ch * 16) : nullptr;
  const int aw0 = ar * 32 + (((ch * 2) ^ ((ar >> 1) & 3)) * 8);
  const int aw1 = ar * 32 + (((ch * 2 + 1) ^ ((ar >> 1) & 3)) * 8);

  f32x4 q0_0, q0_1, q0_2, q0_3;   // 3 named A-reg sets (static indexing, rule #20)
  f32x4 q1_0, q1_1, q1_2, q1_3;
  f32x4 q2_0, q2_1, q2_2, q2_3;

#define ISSUE_B(T) do { \
    gld16(Bsrc0 + (T) * 32, Bs + (((T) & 3) << 13) + tid * 8); \
    gld16(Bsrc1 + (T) * 32, Bs + (((T) & 3) << 13) + tid * 8 + 4096); } while (0)
#define ISSUE_A16(T) do { \
    gld16(Asrc0 + (T) * 32, As + (((T) & 3) << 13) + tid * 8); \
    gld16(Asrc1 + (T) * 32, As + (((T) & 3) << 13) + tid * 8 + 4096); } while (0)
#define ISSUE_P(T, S) do { \
    S##_0 = *(const f32x4*)(apA + (T) * 32); \
    S##_1 = *(const f32x4*)(apA + (T) * 32 + 4); \
    S##_2 = *(const f32x4*)(apA + (T) * 32 + 8); \
    S##_3 = *(const f32x4*)(apA + (T) * 32 + 12); } while (0)
#define CVT_WRITE(T, S) do { \
    u32x4 _w0, _w1; \
    _w0[0] = cvtpk(S##_0[0], S##_0[1]); _w0[1] = cvtpk(S##_0[2], S##_0[3]); \
    _w0[2] = cvtpk(S##_1[0], S##_1[1]); _w0[3] = cvtpk(S##_1[2], S##_1[3]); \
    _w1[0] = cvtpk(S##_2[0], S##_2[1]); _w1[1] = cvtpk(S##_2[2], S##_2[3]); \
    _w1[2] = cvtpk(S##_3[0], S##_3[1]); _w1[3] = cvtpk(S##_3[2], S##_3[3]); \
    *(u32x4*)(As + (((T) & 3) << 13) + aw0) = _w0; \
    *(u32x4*)(As + (((T) & 3) << 13) + aw1) = _w1; } while (0)
#define MFMA_STEP(T) do { \
    const ushort* _a = As + (((T) & 3) << 13); \
    const ushort* _b = Bs + (((T) & 3) << 13); \
    s16x8 fb[4]; \
    _Pragma("unroll") for (int j = 0; j < 4; ++j) \
      fb[j] = *(const s16x8*)(_b + rnb + j * 512 + fro); \
    __builtin_amdgcn_s_setprio(1); \
    _Pragma("unroll") for (int i = 0; i < 8; ++i) { \
      s16x8 fa = *(const s16x8*)(_a + rmb + i * 512 + fro); \
      _Pragma("unroll") for (int j = 0; j < 4; ++j) \
        acc[i][j] = __builtin_amdgcn_mfma_f32_16x16x32_bf16(fa, fb[j], acc[i][j], 0, 0, 0); \
    } \
    __builtin_amdgcn_s_setprio(0); } while (0)

  if constexpr (AFP32) {
    // prologue: [B(s), P(s)] for s = 0..2 (18 loads); cvt A(0)
    ISSUE_B(0); ISSUE_P(0, q0);
    ISSUE_B(1); ISSUE_P(1, q1);
    ISSUE_B(2); ISSUE_P(2, q2);
    CVT_WRITE(0, q0);
#define STEP_F(T, SW, SR) do { \
    WAITVM(16); LGKM0; BARRIER; SBAR; \
    ISSUE_B((T) + 3); ISSUE_P((T) + 3, SW); SBAR; \
    MFMA_STEP(T); \
    CVT_WRITE((T) + 1, SR); } while (0)
#pragma unroll 1
    for (int t = 0; t < 27; t += 3) {
      STEP_F(t, q0, q1);
      STEP_F(t + 1, q1, q2);
      STEP_F(t + 2, q2, q0);
    }
    // t=27: issue B30,P30(set0); cvt A28(set1)
    WAITVM(16); LGKM0; BARRIER; SBAR;
    ISSUE_B(30); ISSUE_P(30, q0); SBAR;
    MFMA_STEP(27); CVT_WRITE(28, q1);
    // t=28: issue B31,P31(set1); cvt A29(set2)
    WAITVM(16); LGKM0; BARRIER; SBAR;
    ISSUE_B(31); ISSUE_P(31, q1); SBAR;
    MFMA_STEP(28); CVT_WRITE(29, q2);
    // t=29: cvt A30(set0)
    WAITVM(16); LGKM0; BARRIER; SBAR;
    MFMA_STEP(29); CVT_WRITE(30, q0);
    // t=30: cvt A31(set1)
    WAITVM(10); LGKM0; BARRIER; SBAR;
    MFMA_STEP(30); CVT_WRITE(31, q1);
    // t=31
    WAITVM(0); LGKM0; BARRIER; SBAR;
    MFMA_STEP(31);
#undef STEP_F
  } else {
    ISSUE_A16(0); ISSUE_B(0);
    ISSUE_A16(1); ISSUE_B(1);
    ISSUE_A16(2); ISSUE_B(2);
#pragma unroll 1
    for (int t = 0; t < 29; ++t) {
      WAITVM(8); LGKM0; BARRIER; SBAR;
      ISSUE_A16(t + 3); ISSUE_B(t + 3); SBAR;
      MFMA_STEP(t);
    }
    WAITVM(8); LGKM0; BARRIER; SBAR; MFMA_STEP(29);
    WAITVM(4); LGKM0; BARRIER; SBAR; MFMA_STEP(30);
    WAITVM(0); LGKM0; BARRIER; SBAR; MFMA_STEP(31);
  }
#undef ISSUE_B
#undef ISSUE_A16
#undef ISSUE_P
#undef CVT_WRITE
#undef MFMA_STEP

  // ---- epilogues: rows m0 + wm*128 + i*16 + fh*4 + r (i<8), cols n0 + wn*64 + j*16 + fl
  if constexpr (EPI == 0) {
    ushort* C = (ushort*)Cv;
#pragma unroll
    for (int j = 0; j < 4; ++j) {
      int col = n0 + wn * 64 + j * 16 + fl;
#pragma unroll
      for (int i = 0; i < 8; ++i)
#pragma unroll
        for (int r = 0; r < 4; ++r) {
          int row = m0 + wm * 128 + i * 16 + fh * 4 + r;
          C[(long)row * N + col] = f2bf(acc[i][j][r]);
        }
    }
  } else if constexpr (EPI == 1) {
    // Q: +bias, softmax over the wave's 64-col head, scale 1/8
    ushort* C = (ushort*)Cv;
    float bcol[4];
#pragma unroll
    for (int j = 0; j < 4; ++j) bcol[j] = bias[n0 + wn * 64 + j * 16 + fl];
#pragma unroll
    for (int i = 0; i < 8; ++i)
#pragma unroll
      for (int r = 0; r < 4; ++r) {
        float v[4];
#pragma unroll
        for (int j = 0; j < 4; ++j) v[j] = acc[i][j][r] + bcol[j];
        float m = fmaxf(fmaxf(v[0], v[1]), fmaxf(v[2], v[3]));
#pragma unroll
        for (int o = 1; o <= 8; o <<= 1) m = fmaxf(m, __shfl_xor(m, o));
        float e[4], s = 0.f;
#pragma unroll
        for (int j = 0; j < 4; ++j) { e[j] = __expf(v[j] - m); s += e[j]; }
#pragma unroll
        for (int o = 1; o <= 8; o <<= 1) s += __shfl_xor(s, o);
        float sc = 0.125f / s;
        int row = m0 + wm * 128 + i * 16 + fh * 4 + r;
#pragma unroll
        for (int j = 0; j < 4; ++j)
          C[(long)row * N + n0 + wn * 64 + j * 16 + fl] = f2bf(e[j] * sc);
      }
  } else if constexpr (EPI == 2) {
    // K: store exp(k); per-128-row-block column partial sums (deterministic)
    ushort* C = (ushort*)Cv;
    float csum[4] = {};
#pragma unroll
    for (int j = 0; j < 4; ++j) {
      int col = n0 + wn * 64 + j * 16 + fl;
#pragma unroll
      for (int i = 0; i < 8; ++i)
#pragma unroll
        for (int r = 0; r < 4; ++r) {
          int row = m0 + wm * 128 + i * 16 + fh * 4 + r;
          float e = __expf(acc[i][j][r]);
          csum[j] += e;
          C[(long)row * N + col] = f2bf(e);
        }
    }
#pragma unroll
    for (int j = 0; j < 4; ++j) {
#pragma unroll
      for (int o = 16; o <= 32; o <<= 1) csum[j] += __shfl_xor(csum[j], o);
    }
    if (fh == 0) {
      int b = m0 >> 12;
      int chunk = ((m0 & 4095) >> 7) + wm;   // 32 chunks of 128 rows per batch
#pragma unroll
      for (int j = 0; j < 4; ++j)
        kpart[(long)b * 32768 + (long)chunk * 1024 + n0 + wn * 64 + j * 16 + fl] = csum[j];
    }
  } else {
    float* C = (float*)Cv + (long)z * sC;
#pragma unroll
    for (int j = 0; j < 4; ++j) {
      int col = n0 + wn * 64 + j * 16 + fl;
      float bv = bias[col];
#pragma unroll
      for (int i = 0; i < 8; ++i)
#pragma unroll
        for (int r = 0; r < 4; ++r) {
          int row = m0 + wm * 128 + i * 16 + fh * 4 + r;
          C[(long)row * N + col] = acc[i][j][r] + bv;
        }
    }
  }
}

// ---------------- colinv[b][d] = 1 / sum_c kpart[b][c][d] ----------------
__global__ void ksm2_kernel(const float* __restrict__ kpart, float* __restrict__ colinv) {
  int idx = blockIdx.x * 256 + threadIdx.x;  // b*1024+d
  int b = idx >> 10, d = idx & 1023;
  float s = 0.f;
  for (int c = 0; c < 32; ++c) s += kpart[(long)b * 32768 + (long)c * 1024 + d];
  colinv[idx] = 1.0f / s;
}

// ---------------- ctx partial: part[chunk][bh][dk][e] = sum_{n in chunk(512)} expk[n,dk]*v[n,e] ----------------
__global__ __launch_bounds__(256, 2) void ctx_partial_kernel(
    const ushort* __restrict__ Ksm, const ushort* __restrict__ Vp, float* __restrict__ part) {
  __shared__ ushort Ks[128 * 64];
  __shared__ ushort Vs[128 * 64];
  const int chunk = blockIdx.x;  // 8 chunks of 512 rows
  const int bh = blockIdx.y;     // 64
  const int b = bh >> 4, h = bh & 15;
  const int tid = threadIdx.x, wave = tid >> 6, lane = tid & 63;
  const int fl = lane & 15, fh = lane >> 4;
  f32x4 acc[4] = {};
  for (int t = 0; t < 4; ++t) {
    const long base = ((long)(b * N_ + chunk * 512 + t * 128)) * D_ + h * 64;
    __syncthreads();
#pragma unroll
    for (int i = 0; i < 4; ++i) {
      int c = i * 256 + tid;
      int r = c >> 3, k8 = (c & 7) * 8;
      ushort* lk = Ks + (long)(i * 256 + wave * 64) * 8;
      ushort* lv = Vs + (long)(i * 256 + wave * 64) * 8;
      gld16(Ksm + base + (long)r * D_ + k8, lk);
      gld16(Vp + base + (long)r * D_ + k8, lv);
    }
    __syncthreads();
#pragma unroll
    for (int s = 0; s < 4; ++s) {
      s16x8 fa;
#pragma unroll
      for (int j = 0; j < 8; ++j)
        fa[j] = (short)Ks[(s * 32 + fh * 8 + j) * 64 + wave * 16 + fl];
#pragma unroll
      for (int jt = 0; jt < 4; ++jt) {
        s16x8 fb;
#pragma unroll
        for (int j = 0; j < 8; ++j)
          fb[j] = (short)Vs[(s * 32 + fh * 8 + j) * 64 + jt * 16 + fl];
        acc[jt] = __builtin_amdgcn_mfma_f32_16x16x32_bf16(fa, fb, acc[jt], 0, 0, 0);
      }
    }
  }
  float* dst = part + ((long)chunk * 64 + bh) * 4096;
#pragma unroll
  for (int jt = 0; jt < 4; ++jt)
#pragma unroll
    for (int r = 0; r < 4; ++r)
      dst[(wave * 16 + fh * 4 + r) * 64 + jt * 16 + fl] = acc[jt][r];
}

// ctxb[bh][dk][e] = bf16( colinv[b,h*64+dk] * sum_ch part + bv[h*64+e] )
__global__ void ctx_reduce_kernel(const float* __restrict__ part, const float* __restrict__ bv,
                                  const float* __restrict__ colinv, ushort* __restrict__ ctxb) {
  int idx = blockIdx.x * 256 + threadIdx.x;
  int e = idx & 63;
  int dk = (idx >> 6) & 63;
  int h = (idx >> 12) & 15;
  int b = idx >> 16;
  float s = 0.f;
#pragma unroll
  for (int c = 0; c < 8; ++c) s += part[(long)c * 262144 + idx];
  ctxb[idx] = f2bf(s * colinv[b * 1024 + h * 64 + dk] + bv[h * 64 + e]);
}

// Mb[b][o, h*64+dk] = sum_e Wo[o, h*64+e] * ctx[b,h][dk,e]
__global__ __launch_bounds__(256, 2) void mb_kernel(
    const ushort* __restrict__ Wob, const ushort* __restrict__ ctxb, ushort* __restrict__ Mb) {
  const int o0 = blockIdx.x * 64, h = blockIdx.y, b = blockIdx.z;
  const int tid = threadIdx.x, wave = tid >> 6, lane = tid & 63;
  const int fl = lane & 15, fh = lane >> 4;
  const ushort* ctxh = ctxb + ((long)(b * 16 + h)) * 4096;
  f32x4 acc[4] = {};
#pragma unroll
  for (int s = 0; s < 2; ++s) {
    s16x8 fa = *(const s16x8*)(Wob + (long)(o0 + wave * 16 + fl) * D_ + h * 64 + s * 32 + fh * 8);
#pragma unroll
    for (int jt = 0; jt < 4; ++jt) {
      s16x8 fb = *(const s16x8*)(ctxh + (long)(jt * 16 + fl) * 64 + s * 32 + fh * 8);
      acc[jt] = __builtin_amdgcn_mfma_f32_16x16x32_bf16(fa, fb, acc[jt], 0, 0, 0);
    }
  }
  ushort* dst = Mb + (long)b * (D_ * D_);
#pragma unroll
  for (int jt = 0; jt < 4; ++jt)
#pragma unroll
    for (int r = 0; r < 4; ++r)
      dst[(long)(o0 + wave * 16 + fh * 4 + r) * D_ + h * 64 + jt * 16 + fl] = f2bf(acc[jt][r]);
}

// ---------------- launch ----------------
extern "C" void kernel_launch(void* const* d_in, const int* in_sizes, int n_in,
                              void* d_out, int out_size, void* d_ws, size_t ws_size,
                              hipStream_t stream) {
  const float* q_in = (const float*)d_in[0];
  const float* k_in = (const float*)d_in[1];
  const float* v_in = (const float*)d_in[2];
  const float* Wq = (const float*)d_in[3];
  const float* bq = (const float*)d_in[4];
  const float* Wk = (const float*)d_in[5];
  const float* Wv = (const float*)d_in[7];
  const float* bv = (const float*)d_in[8];
  const float* Wo = (const float*)d_in[9];
  const float* bo = (const float*)d_in[10];

  char* ws = (char*)d_ws;
  ushort* Wb = (ushort*)(ws + 0);              // 8 MB
  ushort* Qp = (ushort*)(ws + 8388608);        // 32 MB
  ushort* Kp = (ushort*)(ws + 41943040);       // 32 MB
  ushort* Vp = (ushort*)(ws + 75497472);       // 32 MB
  float* kpart = (float*)(ws + 109051904);     // [4][32][1024] f32 = 512 KB
  float* colinv = (float*)(ws + 109576192);    // 16 KB
  float* ctxpart = (float*)(ws + 109592576);   // [8][64][4096] f32 = 8 MB
  ushort* ctxb = (ushort*)(ws + 117981184);    // 512 KB
  ushort* Mb = (ushort*)(ws + 118505472);      // 8 MB

  ushort* Wbq = Wb;
  ushort* Wbk = Wb + 1048576;
  ushort* Wbv = Wb + 2097152;
  ushort* Wbo = Wb + 3145728;

  conv_w_kernel<<<dim3(128, 1, 4), 256, 0, stream>>>(Wq, Wk, Wv, Wo, Wb);

  // projections: fp32 A read directly; M=16384 (64 m-tiles), N=1024 (4 n-tiles)
  gemm_bt_kernel<1, true><<<dim3(64, 4, 1), 512, 0, stream>>>(
      q_in, Wbq, Qp, bq, nullptr, 0, 0, 0);
  gemm_bt_kernel<2, true><<<dim3(64, 4, 1), 512, 0, stream>>>(
      k_in, Wbk, Kp, nullptr, kpart, 0, 0, 0);
  gemm_bt_kernel<0, true><<<dim3(64, 4, 1), 512, 0, stream>>>(
      v_in, Wbv, Vp, nullptr, nullptr, 0, 0, 0);

  ksm2_kernel<<<16, 256, 0, stream>>>(kpart, colinv);

  ctx_partial_kernel<<<dim3(8, 64), 256, 0, stream>>>(Kp, Vp, ctxpart);
  ctx_reduce_kernel<<<1024, 256, 0, stream>>>(ctxpart, bv, colinv, ctxb);
  mb_kernel<<<dim3(16, 16, 4), 256, 0, stream>>>(Wbo, ctxb, Mb);

  // final: per-batch out = Qp_b @ Mb_b^T + bo (fp32 out); 16 m-tiles x 4 n-tiles x 4 batches
  gemm_bt_kernel<3, false><<<dim3(16, 4, 4), 512, 0, stream>>>(
      Qp, Mb, (float*)d_out, bo, nullptr,
      (long)4096 * 1024, (long)1024 * 1024, (long)4096 * 1024);
}